// Round 7
// baseline (60.369 us; speedup 1.0000x reference)
//
#include <hip/hip_runtime.h>
#include <hip/hip_bf16.h>
#include <stdint.h>

typedef __bf16 v8bf __attribute__((ext_vector_type(8)));
typedef float  v4f  __attribute__((ext_vector_type(4)));

#define LEAK 0.2f

static __device__ __forceinline__ unsigned short bf16rne(float f) {
    union { float f; uint32_t u; } v; v.f = f;
    return (unsigned short)((v.u + 0x7FFFu + ((v.u >> 16) & 1u)) >> 16);
}
static __device__ __forceinline__ float bf2f(unsigned short s) {
    union { uint32_t u; float f; } v; v.u = (uint32_t)s << 16; return v.f;
}
static __device__ __forceinline__ void gload16(const void* g, void* l) {
    __builtin_amdgcn_global_load_lds(
        (const __attribute__((address_space(1))) void*)g,
        (__attribute__((address_space(3))) void*)l, 16, 0, 0);
}

// ---------------------------------------------------------------------------
// K1: Yt[j][n*60+lt] = bf16( sum_i x[n,i]*W[i,c] ), c = j*60+lt.  (R6-proven)
// ---------------------------------------------------------------------------
__global__ __launch_bounds__(256) void k1_ygemm(const float* __restrict__ x,
                                                const float* __restrict__ W,
                                                unsigned short* __restrict__ Yt) {
    __shared__ __align__(16) char lds[24576];   // xs f32 16KB | wt bf16 8KB
    const int blk = blockIdx.x;
    const int nt = blk / 60, ct = blk % 60;
    const int n0 = nt * 64, c0 = ct * 64;
    const int t = threadIdx.x;
    const int w = t >> 6, l = t & 63;
    const int lr = l & 15, lg = l >> 4;

#pragma unroll
    for (int k = 0; k < 4; ++k) {
        const int row = k * 16 + w * 4 + lg;
        const char* src = (const char*)(x + (size_t)(n0 + row) * 64)
                          + ((lr * 16) ^ ((row & 7) << 4));
        gload16(src, lds + k * 4096 + w * 1024);
    }
#pragma unroll
    for (int r = 0; r < 4; ++r) {
        const int q = t + (r << 8);
        const int i = q >> 4;
        const int c4 = (q & 15) << 2;
        const float4 v = *reinterpret_cast<const float4*>(W + (size_t)i * 3840 + c0 + c4);
        const unsigned short b0 = bf16rne(v.x), b1 = bf16rne(v.y);
        const unsigned short b2 = bf16rne(v.z), b3 = bf16rne(v.w);
#pragma unroll
        for (int e = 0; e < 4; ++e) {
            const int c = c4 + e;
            const unsigned short bv = (e == 0) ? b0 : (e == 1) ? b1 : (e == 2) ? b2 : b3;
            *(unsigned short*)(lds + 16384 + c * 128 + ((i * 2) ^ ((c & 7) << 4))) = bv;
        }
    }
    __syncthreads();

    v4f acc[4];
#pragma unroll
    for (int jt = 0; jt < 4; ++jt) acc[jt] = (v4f){0.f, 0.f, 0.f, 0.f};

    const int ar = 16 * w + lr;
    const int sa = (ar & 7) << 4;

#pragma unroll
    for (int s = 0; s < 2; ++s) {
        const int Xf = s * 128 + lg * 32;
        const float4 x0 = *reinterpret_cast<const float4*>(lds + ar * 256 + (Xf ^ sa));
        const float4 x1 = *reinterpret_cast<const float4*>(lds + ar * 256 + ((Xf + 16) ^ sa));
        v8bf af;
        af[0] = (__bf16)x0.x; af[1] = (__bf16)x0.y;
        af[2] = (__bf16)x0.z; af[3] = (__bf16)x0.w;
        af[4] = (__bf16)x1.x; af[5] = (__bf16)x1.y;
        af[6] = (__bf16)x1.z; af[7] = (__bf16)x1.w;

#pragma unroll
        for (int jt = 0; jt < 4; ++jt) {
            const int c = jt * 16 + lr;
            const v8bf bf = *reinterpret_cast<const v8bf*>(
                lds + 16384 + c * 128 + ((s * 64 + lg * 16) ^ ((c & 7) << 4)));
            acc[jt] = __builtin_amdgcn_mfma_f32_16x16x32_bf16(af, bf, acc[jt], 0, 0, 0);
        }
    }

#pragma unroll
    for (int jt = 0; jt < 4; ++jt) {
#pragma unroll
        for (int r = 0; r < 4; ++r) {
            const int n = n0 + 16 * w + lg * 4 + r;
            const int c = c0 + jt * 16 + lr;
            const int j = c / 60, lt = c % 60;
            Yt[j * 61440 + n * 60 + lt] = bf16rne(acc[jt][r]);
        }
    }
}

// ---------------------------------------------------------------------------
// K2: split-K GEMM.  BK=32, 6 LDS buffers, depth-5 counted-vmcnt(12) DMA
// pipeline, 60 steps, 1 s_barrier/step.  Same math order as R6 (bit-identical
// output).  A buf: 64x32 f32 = 8KB (128B rows, XOR ((r&7)<<4) via source).
// B buf: 64x32 bf16 = 4KB, pair-packed: byte(j,kb) = (j>>1)*128 +
//        (((j&1)*64 + kb) ^ (((j>>1)&7)<<4)).
// grid 512 = 16 m-tiles * 32 k-splits, 256 threads.
// ---------------------------------------------------------------------------
__global__ __launch_bounds__(256) void k2_main(const float* __restrict__ adj,
                                               const unsigned short* __restrict__ Yt,
                                               unsigned short* __restrict__ partial) {
    __shared__ __align__(16) char lds[73728];   // A: 6*8KB @0, B: 6*4KB @49152
    const int blk = blockIdx.x;
    const int mt = blk >> 5, ks = blk & 31;     // blk%8 == ks%8 -> Yt XCD locality
    const int m0 = mt * 64;
    const long kc0 = (long)ks * 1920;
    const int t = threadIdx.x;
    const int w = t >> 6, l = t & 63;
    const int lr = l & 15, lg = l >> 4;

    // A staging sources: row r = k_*32 + w*8 + (l>>3), col ((l&7)*16)^((r&7)<<4)
    const char* srcA0;
    const char* srcA1;
    {
        const int r0 = w * 8 + (l >> 3);
        const int r1 = 32 + r0;
        srcA0 = (const char*)(adj + (size_t)(m0 + r0) * 61440 + kc0)
                + (((l & 7) * 16) ^ ((r0 & 7) << 4));
        srcA1 = (const char*)(adj + (size_t)(m0 + r1) * 61440 + kc0)
                + (((l & 7) * 16) ^ ((r1 & 7) << 4));
    }
    // B staging source (pair-packed layout, see header comment)
    const char* srcB;
    {
        const int sinner = ((l & 7) << 4) ^ (((l >> 3) & 7) << 4);
        const int brow = 2 * (w * 8 + (l >> 3)) + ((sinner >> 6) & 1);
        const int bkb = sinner & 63;
        srcB = (const char*)(Yt + (size_t)brow * 61440 + kc0) + bkb;
    }

#define STAGE(bs, s) do {                                            \
        char* ab_ = lds + (bs) * 8192;                               \
        char* bb_ = lds + 49152 + (bs) * 4096;                       \
        gload16(srcA0 + (size_t)(s) * 128, ab_ + w * 1024);          \
        gload16(srcA1 + (size_t)(s) * 128, ab_ + 4096 + w * 1024);   \
        gload16(srcB  + (size_t)(s) * 64,  bb_ + w * 1024);          \
    } while (0)

    v4f acc[4];
#pragma unroll
    for (int jt = 0; jt < 4; ++jt) acc[jt] = (v4f){0.f, 0.f, 0.f, 0.f};

    const int ar = 16 * w + lr;
    const int sa = (ar & 7) << 4;

#define COMPUTE(bc) do {                                                            \
        const char* ab = lds + (bc) * 8192;                                         \
        const char* bb = lds + 49152 + (bc) * 4096;                                 \
        const float4 x0 = *reinterpret_cast<const float4*>(                         \
            ab + ar * 128 + ((lg * 32) ^ sa));                                      \
        const float4 x1 = *reinterpret_cast<const float4*>(                         \
            ab + ar * 128 + ((lg * 32 + 16) ^ sa));                                 \
        v8bf af;                                                                    \
        af[0] = (__bf16)x0.x; af[1] = (__bf16)x0.y;                                 \
        af[2] = (__bf16)x0.z; af[3] = (__bf16)x0.w;                                 \
        af[4] = (__bf16)x1.x; af[5] = (__bf16)x1.y;                                 \
        af[6] = (__bf16)x1.z; af[7] = (__bf16)x1.w;                                 \
        _Pragma("unroll")                                                           \
        for (int jt = 0; jt < 4; ++jt) {                                            \
            const int br = jt * 16 + lr;                                            \
            const v8bf bf = *reinterpret_cast<const v8bf*>(                         \
                bb + (br >> 1) * 128 +                                              \
                ((((br & 1) * 64) + lg * 16) ^ (((br >> 1) & 7) << 4)));            \
            acc[jt] = __builtin_amdgcn_mfma_f32_16x16x32_bf16(af, bf, acc[jt],      \
                                                              0, 0, 0);             \
        }                                                                           \
    } while (0)

#define WAITB(N) do {                                               \
        asm volatile("s_waitcnt vmcnt(" #N ")" ::: "memory");       \
        __builtin_amdgcn_s_barrier();                               \
        asm volatile("" ::: "memory");                              \
    } while (0)

    STAGE(0, 0); STAGE(1, 1); STAGE(2, 2); STAGE(3, 3); STAGE(4, 4);

    // main: ii = 0..8, i = ii*6+u (0..53); stage i+5 (<=58); all buf idx static
#pragma unroll 1
    for (int ii = 0; ii < 9; ++ii) {
        const int ib = ii * 6;
#pragma unroll
        for (int u = 0; u < 6; ++u) {
            WAITB(12);
            STAGE((u + 5) % 6, ib + u + 5);
            COMPUTE(u);
        }
    }
    // tail: i = 54..59
    WAITB(12); STAGE(5, 59); COMPUTE(0);   // i=54
    WAITB(12); COMPUTE(1);                 // i=55
    WAITB(9);  COMPUTE(2);                 // i=56
    WAITB(6);  COMPUTE(3);                 // i=57
    WAITB(3);  COMPUTE(4);                 // i=58
    WAITB(0);  COMPUTE(5);                 // i=59

#undef WAITB
#undef COMPUTE
#undef STAGE

    unsigned short* const p = partial + (size_t)ks * 65536;
#pragma unroll
    for (int jt = 0; jt < 4; ++jt) {
#pragma unroll
        for (int r = 0; r < 4; ++r) {
            const int m = m0 + 16 * w + lg * 4 + r;
            const int j = jt * 16 + lr;
            p[m * 64 + j] = bf16rne(acc[jt][r]);
        }
    }
}

// ---------------------------------------------------------------------------
// K3: out = lrelu( sum_splits partial(bf16) + x @ W2 ).  256 blocks, 1 (m,j)
// per thread; m wave-uniform, all loads wave-contiguous.
// ---------------------------------------------------------------------------
__global__ __launch_bounds__(256) void k3_epi(const unsigned short* __restrict__ partial,
                                              const float* __restrict__ x,
                                              const float* __restrict__ W2,
                                              float* __restrict__ out) {
    const int idx = blockIdx.x * 256 + threadIdx.x;   // 0..65535
    const int m = idx >> 6, j = idx & 63;

    float s = 0.f;
#pragma unroll 8
    for (int sp = 0; sp < 32; ++sp) s += bf2f(partial[(size_t)sp * 65536 + idx]);

    const float* xrow = x + m * 64;
#pragma unroll 8
    for (int i = 0; i < 64; ++i) s += xrow[i] * W2[i * 64 + j];

    out[idx] = fmaxf(s, LEAK * s);
}

// ---------------------------------------------------------------------------
extern "C" void kernel_launch(void* const* d_in, const int* in_sizes, int n_in,
                              void* d_out, int out_size, void* d_ws, size_t ws_size,
                              hipStream_t stream) {
    const float* x   = (const float*)d_in[0];
    const float* adj = (const float*)d_in[1];
    const float* W   = (const float*)d_in[2];
    const float* W2  = (const float*)d_in[3];
    float* out = (float*)d_out;

    char* ws = (char*)d_ws;
    unsigned short* Yt      = (unsigned short*)ws;               // 7,864,320 B
    unsigned short* partial = (unsigned short*)(ws + 7864320);   // 4,194,304 B

    k1_ygemm<<<960, 256, 0, stream>>>(x, W, Yt);
    k2_main <<<512, 256, 0, stream>>>(adj, Yt, partial);
    k3_epi  <<<256, 256, 0, stream>>>(partial, x, W2, out);
}